// Round 1
// baseline (406.970 us; speedup 1.0000x reference)
//
#include <hip/hip_runtime.h>

// GraphSageConvOD: 2-iteration OD flow + SIR propagation + 12x64 dense + ReLU.
// B=8, T=2, N=2048. OD_all is 256 MB fp32; memory-bound.
//
// Measured budget: ~325 us of the ~399 us is harness ws-poison fills
// (2 x 1 GiB @ ~6.6 TB/s, visible in rocprof as fillBufferAligned); the
// kernel-side floor is ~48 us (268.7 MB OD reads @ 6.3 TB/s + LLC partials).
//
// R6 changes vs R5:
//   - fused0/fused1: ONE barrier per 8-row group (double-buffered wpart,
//     every thread redundantly derives scale/w from broadcast LDS partials;
//     removes the tid<8 serialization + 8 barriers/kernel). Prefetch of
//     group g+1 issued AFTER the barrier so it overlaps the consume phase.
//   - final2: rewritten. 256 blocks x 512 threads, 64 points/block; the
//     part1 rb-reduction is fully coalesced (thread t owns float t of the
//     block's 512-float slice; 32 independent loads tree-reduced), then an
//     LDS-staged 12x64 GEMM. Old version was 4096 tiny blocks with 64 KB-
//     strided float4 gathers (2x line over-read on 16 MB).

#define DELTA 1e-7f
constexpr int B = 8, N = 2048;
constexpr int NB = B * N;     // 16384
constexpr int RPB = 64;       // rows per block (fused kernels)
constexpr int NRB = N / RPB;  // 32 row-blocks per batch
constexpr int PPB = 64;       // points per block (final2)

// ws float offsets
constexpr int ST0_OFF = 0;                     // [b][i][4] {pm0, stay0[3]}
constexpr int ST1_OFF = ST0_OFF + NB * 4;      // [b][i][8] {pm1, stay1[0..5], 0}
constexpr int P0_OFF  = ST1_OFF + NB * 8;      // part0 [b][rb][j][4]
constexpr int P1_OFF  = P0_OFF + B * NRB * N * 4;  // part1 [b][rb][j][8]

__device__ __forceinline__ void fma4(float4& a, float s, const float4& w) {
  a.x = fmaf(s, w.x, a.x);
  a.y = fmaf(s, w.y, a.y);
  a.z = fmaf(s, w.z, a.z);
  a.w = fmaf(s, w.w, a.w);
}
__device__ __forceinline__ void add4(float4& a, const float4& v) {
  a.x += v.x; a.y += v.y; a.z += v.z; a.w += v.w;
}

// ---- fused0: t=0 rowsum + scale + column partials, OD0 read once ----
__global__ void __launch_bounds__(512) fused0_kernel(const float* __restrict__ OD,
                                                     const float* __restrict__ feat,
                                                     float* __restrict__ part0,
                                                     float* __restrict__ st0) {
  const int tid = threadIdx.x, w = tid >> 6, l = tid & 63;
  const int b = blockIdx.x >> 5, rb = blockIdx.x & 31, i0 = rb * RPB;
  __shared__ float4 ldsfeat[RPB];
  __shared__ float ldsinv[RPB];
  __shared__ float wpart[2][64];
  if (tid < RPB) {
    const float4 f = ((const float4*)feat)[b * N + i0 + tid];
    ldsfeat[tid] = f;
    ldsinv[tid] = 1.f / (DELTA + f.x);
  }
  __syncthreads();

  const float* odbase = OD + ((size_t)(b * 2) * N + i0) * N + w * 256 + l * 4;
  float4 acc[4] = {};
  float4 cur[8], nxt[8];
#pragma unroll
  for (int m = 0; m < 8; ++m) cur[m] = *(const float4*)(odbase + (size_t)m * N);

  for (int g = 0; g < 8; ++g) {
    // per-wave row partials -> LDS (double-buffered; one barrier per group)
#pragma unroll
    for (int m = 0; m < 8; ++m) {
      float s = (cur[m].x + cur[m].y) + (cur[m].z + cur[m].w);
#pragma unroll
      for (int off = 32; off; off >>= 1) s += __shfl_down(s, off, 64);
      if (l == 0) wpart[g & 1][w * 8 + m] = s;
    }
    __syncthreads();
    if (g < 7) {  // prefetch overlaps the w-compute + fma consume below
#pragma unroll
      for (int m = 0; m < 8; ++m)
        nxt[m] = *(const float4*)(odbase + (size_t)((g + 1) * 8 + m) * N);
    }
#pragma unroll
    for (int m = 0; m < 8; ++m) {
      const int r = g * 8 + m;
      float rs = 0.f;
#pragma unroll
      for (int ww = 0; ww < 8; ++ww) rs += wpart[g & 1][ww * 8 + m];  // broadcast
      const float4 f = ldsfeat[r];
      const float inv = ldsinv[r];
      const float ratio = f.x / (DELTA + rs);
      const float scale = ratio < 1.f ? ratio : 1.f;
      const float si = scale * inv;
      const float4 wv = make_float4(scale, f.y * si, f.z * si, f.w * si);
      fma4(acc[0], cur[m].x, wv);
      fma4(acc[1], cur[m].y, wv);
      fma4(acc[2], cur[m].z, wv);
      fma4(acc[3], cur[m].w, wv);
      if (tid == m) {  // one lane stores this row's state
        const float odout = scale * rs;
        const float k1 = 1.f - odout * inv;
        ((float4*)st0)[b * N + i0 + r] =
            make_float4(f.x - odout, f.y * k1, f.z * k1, f.w * k1);
      }
    }
    if (g < 7) {
#pragma unroll
      for (int m = 0; m < 8; ++m) cur[m] = nxt[m];
    }
  }
  float4* pb = (float4*)part0 + (size_t)blockIdx.x * N + (w * 256 + l * 4);
#pragma unroll
  for (int c = 0; c < 4; ++c) pb[c] = acc[c];
}

// ---- fused1: prologue (prep1 in LDS) + t=1 rowsum/scale/col-partials ----
__global__ void __launch_bounds__(512) fused1_kernel(const float* __restrict__ OD,
                                                     const float* __restrict__ st0,
                                                     const float* __restrict__ part0,
                                                     float* __restrict__ part1,
                                                     float* __restrict__ st1) {
  const int tid = threadIdx.x, w = tid >> 6, l = tid & 63;
  const int b = blockIdx.x >> 5, rb = blockIdx.x & 31, i0 = rb * RPB;
  __shared__ float ldspre[RPB * 8];
  __shared__ float4 redp[8][RPB];
  __shared__ float wpart[2][64];

  // prologue: in[b][i][4] = sum_rbp part0[b][rbp][i][4] for this block's rows
  {
    const int row = tid & 63, rbg = tid >> 6;  // 8 groups of 4 rbp each
    const float4* p0 = (const float4*)part0 + (size_t)b * NRB * N + i0 + row;
    float4 s = {0.f, 0.f, 0.f, 0.f};
#pragma unroll
    for (int k = 0; k < 4; ++k) add4(s, p0[(size_t)(rbg * 4 + k) * N]);
    redp[rbg][row] = s;
  }
  __syncthreads();
  if (tid < RPB) {
    float4 in = redp[0][tid];
#pragma unroll
    for (int g = 1; g < 8; ++g) add4(in, redp[g][tid]);
    const float4 s0 = ((const float4*)st0)[b * N + i0 + tid];
    const float pop = s0.x + in.x;  // pm0 + OD_in0
    const float inv = 1.f / (DELTA + pop);
    float* o = &ldspre[tid * 8];
    o[0] = pop; o[1] = inv;
    o[2] = s0.y; o[3] = s0.z; o[4] = s0.w;
    o[5] = in.y; o[6] = in.z; o[7] = in.w;
  }
  __syncthreads();

  const float* odbase = OD + ((size_t)(b * 2 + 1) * N + i0) * N + w * 256 + l * 4;
  float4 accA[4] = {}, accB[4] = {};
  float4 cur[8], nxt[8];
#pragma unroll
  for (int m = 0; m < 8; ++m) cur[m] = *(const float4*)(odbase + (size_t)m * N);

  for (int g = 0; g < 8; ++g) {
#pragma unroll
    for (int m = 0; m < 8; ++m) {
      float s = (cur[m].x + cur[m].y) + (cur[m].z + cur[m].w);
#pragma unroll
      for (int off = 32; off; off >>= 1) s += __shfl_down(s, off, 64);
      if (l == 0) wpart[g & 1][w * 8 + m] = s;
    }
    __syncthreads();
    if (g < 7) {  // prefetch overlaps the consume phase
#pragma unroll
      for (int m = 0; m < 8; ++m)
        nxt[m] = *(const float4*)(odbase + (size_t)((g + 1) * 8 + m) * N);
    }
#pragma unroll
    for (int m = 0; m < 8; ++m) {
      const int r = g * 8 + m;
      float rs = 0.f;
#pragma unroll
      for (int ww = 0; ww < 8; ++ww) rs += wpart[g & 1][ww * 8 + m];  // broadcast
      const float* pr = &ldspre[r * 8];  // broadcast reads
      const float pop = pr[0], inv = pr[1];
      const float ratio = pop / (DELTA + rs);
      const float scale = ratio < 1.f ? ratio : 1.f;
      const float si = scale * inv;
      const float4 wa = make_float4(scale, pr[2] * si, pr[3] * si, pr[4] * si);
      const float4 wb = make_float4(pr[5] * si, pr[6] * si, pr[7] * si, 0.f);
      fma4(accA[0], cur[m].x, wa);
      fma4(accB[0], cur[m].x, wb);
      fma4(accA[1], cur[m].y, wa);
      fma4(accB[1], cur[m].y, wb);
      fma4(accA[2], cur[m].z, wa);
      fma4(accB[2], cur[m].z, wb);
      fma4(accA[3], cur[m].w, wa);
      fma4(accB[3], cur[m].w, wb);
      if (tid == m) {
        const float odout = scale * rs;
        const float k1 = 1.f - odout * inv;
        float4* s4 = (float4*)st1 + (size_t)(b * N + i0 + r) * 2;
        s4[0] = make_float4(pop - odout, pr[2] * k1, pr[3] * k1, pr[4] * k1);
        s4[1] = make_float4(pr[5] * k1, pr[6] * k1, pr[7] * k1, 0.f);
      }
    }
    if (g < 7) {
#pragma unroll
      for (int m = 0; m < 8; ++m) cur[m] = nxt[m];
    }
  }
  float4* pb = (float4*)part1 + ((size_t)blockIdx.x * N + (w * 256 + l * 4)) * 2;
#pragma unroll
  for (int c = 0; c < 4; ++c) {
    pb[c * 2] = accA[c];
    pb[c * 2 + 1] = accB[c];
  }
}

// ---- final2: coalesced reduce of part1 over rb + dense 12x64 + relu ----
// 256 blocks x 512 threads; each block owns 64 consecutive points.
// part1 record for point j is 8 contiguous floats {A.xyzw, B.xyzw}; thread t
// owns float (t&7) of point (t>>3), so each rb-step reads 2048 contiguous B.
__global__ void __launch_bounds__(512) final2_kernel(const float* __restrict__ st1,
                                                     const float* __restrict__ part1,
                                                     const float* __restrict__ kern,
                                                     const float* __restrict__ bias,
                                                     float* __restrict__ out) {
  __shared__ float klds[12 * 64];
  __shared__ float s13[PPB][13];  // [stay0..5, in0..5, pop2]
  const int tid = threadIdx.x;
  const int p0 = blockIdx.x * PPB;  // never crosses a batch (2048 % 64 == 0)
  const int b = p0 >> 11, j0 = p0 & (N - 1);
  if (tid < 192) ((float4*)klds)[tid] = ((const float4*)kern)[tid];

  const int j = tid >> 3, f = tid & 7;
  const float sv = st1[(size_t)p0 * 8 + tid];  // coalesced 2 KB
  if (f >= 1 && f <= 6) s13[j][f - 1] = sv;    // stay[0..5]

  // coalesced reduction over the 32 row-block partials (tree order)
  const float* pbase = part1 + ((size_t)(b * NRB) * N + j0) * 8 + tid;
  float v[NRB];
#pragma unroll
  for (int r = 0; r < NRB; ++r) v[r] = pbase[(size_t)r * N * 8];
#pragma unroll
  for (int s = 1; s < NRB; s <<= 1) {
#pragma unroll
    for (int i = 0; i < NRB; i += 2 * s) v[i] += v[i + s];
  }
  const float acc = v[0];

  if (f == 0) s13[j][12] = sv + acc;      // pop2 = pm1 + OD_in1 (accA.x)
  else if (f <= 3) s13[j][5 + f] = acc;   // in[0..2] = accA.yzw
  else if (f <= 6) s13[j][5 + f] = acc;   // in[3..5] = accB.xyz
  // f == 7: accB.w partials are all zero
  __syncthreads();

  const int c = tid & 63, pg = tid >> 6;  // wave pg handles points pg*8..pg*8+7
  const float bb = bias[c];
#pragma unroll
  for (int k = 0; k < 8; ++k) {
    const int jp = pg * 8 + k;
    float sum = bb;
#pragma unroll
    for (int ff = 0; ff < 12; ++ff)
      sum += s13[jp][ff] * klds[ff * 64 + c];  // broadcast x stride-1
    float* o = out + (size_t)(p0 + jp) * 65;
    o[1 + c] = sum > 0.f ? sum : 0.f;
    if (c == 0) o[0] = s13[jp][12];
  }
}

extern "C" void kernel_launch(void* const* d_in, const int* in_sizes, int n_in,
                              void* d_out, int out_size, void* d_ws, size_t ws_size,
                              hipStream_t stream) {
  const float* feat = (const float*)d_in[0];  // (8,2048,4)
  const float* OD   = (const float*)d_in[1];  // (8,2,2048,2048)
  const float* kern = (const float*)d_in[2];  // (12,64)
  const float* bias = (const float*)d_in[3];  // (64,)
  float* out = (float*)d_out;                 // (8,2048,65)
  float* ws = (float*)d_ws;

  float* st0   = ws + ST0_OFF;
  float* st1   = ws + ST1_OFF;
  float* part0 = ws + P0_OFF;
  float* part1 = ws + P1_OFF;

  fused0_kernel<<<B * NRB, 512, 0, stream>>>(OD, feat, part0, st0);
  fused1_kernel<<<B * NRB, 512, 0, stream>>>(OD, st0, part0, part1, st1);
  final2_kernel<<<NB / PPB, 512, 0, stream>>>(st1, part1, kern, bias, out);
}